// Round 1
// baseline (438.876 us; speedup 1.0000x reference)
//
#include <hip/hip_runtime.h>

#define N_NODES 4096
#define EPS 0.005f
#define TH0 0.4f
#define TH1 0.24f
#define TH2 0.144f
#define TH3 0.0864f

// ws layout (byte offsets):
//   0        counts  int[4096]          (zeroed via hipMemsetAsync)
//   16K      row_ptr int[4097]
//   48K      cursor  int[4096]
//   64K      col     int[E]             (E = 131072 -> 512KB)
//   64K+4E   val     float[E]           (512KB)
//   2M       m2      float[N*N]         (64MB, dense thresholded A@A)

__global__ void hist_kernel(const int* __restrict__ idx, int E,
                            int* __restrict__ counts) {
    int e = blockIdx.x * blockDim.x + threadIdx.x;
    if (e < E) atomicAdd(&counts[idx[e]], 1);
}

__global__ __launch_bounds__(1024)
void scan_kernel(const int* __restrict__ counts, int* __restrict__ row_ptr,
                 int* __restrict__ cursor) {
    __shared__ int lds[1024];
    int t = threadIdx.x;
    int c0 = counts[4 * t + 0];
    int c1 = counts[4 * t + 1];
    int c2 = counts[4 * t + 2];
    int c3 = counts[4 * t + 3];
    int s = c0 + c1 + c2 + c3;
    lds[t] = s;
    __syncthreads();
    for (int off = 1; off < 1024; off <<= 1) {
        int v = 0;
        if (t >= off) v = lds[t - off];
        __syncthreads();
        lds[t] += v;
        __syncthreads();
    }
    int incl = lds[t];
    int base = incl - s;                 // exclusive prefix of this thread's 4
    int r0 = base;
    int r1 = base + c0;
    int r2 = r1 + c1;
    int r3 = r2 + c2;
    row_ptr[4 * t + 0] = r0;  cursor[4 * t + 0] = r0;
    row_ptr[4 * t + 1] = r1;  cursor[4 * t + 1] = r1;
    row_ptr[4 * t + 2] = r2;  cursor[4 * t + 2] = r2;
    row_ptr[4 * t + 3] = r3;  cursor[4 * t + 3] = r3;
    if (t == 1023) row_ptr[N_NODES] = incl;
}

__global__ void scatter_kernel(const int* __restrict__ idx,
                               const float* __restrict__ attr, int E,
                               int* __restrict__ cursor, int* __restrict__ col,
                               float* __restrict__ val) {
    int e = blockIdx.x * blockDim.x + threadIdx.x;
    if (e < E) {
        int s = idx[e];
        int d = idx[e + E];
        int pos = atomicAdd(&cursor[s], 1);
        col[pos] = d;
        val[pos] = attr[e];
    }
}

// M2 = threshold(A @ A), one block per row, dense LDS accumulator.
__global__ __launch_bounds__(256)
void m2_kernel(const int* __restrict__ row_ptr, const int* __restrict__ col,
               const float* __restrict__ val, float* __restrict__ m2) {
    __shared__ float acc[N_NODES];
    __shared__ int   kcol[256];
    __shared__ float kval[256];
    int i = blockIdx.x;
    int t = threadIdx.x;
    for (int j = t; j < N_NODES; j += 256) acc[j] = 0.0f;
    __syncthreads();
    int e0 = row_ptr[i], e1 = row_ptr[i + 1];
    for (int base = e0; base < e1; base += 256) {
        int n = min(256, e1 - base);
        if (t < n) { kcol[t] = col[base + t]; kval[t] = val[base + t]; }
        __syncthreads();
        for (int q = 0; q < n; q++) {
            int k = kcol[q];
            float a = kval[q];
            int f0 = row_ptr[k], f1 = row_ptr[k + 1];
            for (int f = f0 + t; f < f1; f += 256) {
                atomicAdd(&acc[col[f]], a * val[f]);
            }
        }
        __syncthreads();
    }
    size_t rb = (size_t)i * N_NODES;
    for (int j = t; j < N_NODES; j += 256) {
        float v = acc[j];
        m2[rb + j] = (v >= EPS) ? v : 0.0f;
    }
}

// out row i = TH0*P0 + TH1*A + TH2*M2 + TH3*thr(A @ M2)
// Register-blocked dense gather: thread t owns cols {c*1024 + 4t .. +3}, c=0..3.
__global__ __launch_bounds__(256)
void out_kernel(const int* __restrict__ row_ptr, const int* __restrict__ col,
                const float* __restrict__ val, const float* __restrict__ m2,
                float* __restrict__ out) {
    __shared__ float ap[N_NODES];
    __shared__ int   kcol[256];
    __shared__ float kval[256];
    int i = blockIdx.x;
    int t = threadIdx.x;
    for (int j = t; j < N_NODES; j += 256) ap[j] = 0.0f;
    __syncthreads();
    int e0 = row_ptr[i], e1 = row_ptr[i + 1];
    float4 a0 = make_float4(0.f, 0.f, 0.f, 0.f);
    float4 a1 = a0, a2 = a0, a3 = a0;
    for (int base = e0; base < e1; base += 256) {
        int n = min(256, e1 - base);
        if (t < n) {
            int c = col[base + t];
            float v = val[base + t];
            kcol[t] = c;
            kval[t] = v;
            atomicAdd(&ap[c], TH0 + TH1 * v);   // P0 + A contribution (dups add)
        }
        __syncthreads();
        for (int q = 0; q < n; q++) {
            int k = kcol[q];
            float a = kval[q];
            const float4* r = (const float4*)(m2 + (size_t)k * N_NODES);
            float4 v0 = r[t];
            float4 v1 = r[256 + t];
            float4 v2 = r[512 + t];
            float4 v3 = r[768 + t];
            a0.x = fmaf(a, v0.x, a0.x); a0.y = fmaf(a, v0.y, a0.y);
            a0.z = fmaf(a, v0.z, a0.z); a0.w = fmaf(a, v0.w, a0.w);
            a1.x = fmaf(a, v1.x, a1.x); a1.y = fmaf(a, v1.y, a1.y);
            a1.z = fmaf(a, v1.z, a1.z); a1.w = fmaf(a, v1.w, a1.w);
            a2.x = fmaf(a, v2.x, a2.x); a2.y = fmaf(a, v2.y, a2.y);
            a2.z = fmaf(a, v2.z, a2.z); a2.w = fmaf(a, v2.w, a2.w);
            a3.x = fmaf(a, v3.x, a3.x); a3.y = fmaf(a, v3.y, a3.y);
            a3.z = fmaf(a, v3.z, a3.z); a3.w = fmaf(a, v3.w, a3.w);
        }
        __syncthreads();
    }
    const float4* mi = (const float4*)(m2 + (size_t)i * N_NODES);
    float4* o = (float4*)(out + (size_t)i * N_NODES);
    const float4* apv = (const float4*)ap;
    float4 accs[4] = {a0, a1, a2, a3};
    for (int c = 0; c < 4; c++) {
        int fi = c * 256 + t;
        float4 m = mi[fi];
        float4 p = apv[fi];
        float4 s = accs[c];
        float4 res;
        res.x = p.x + TH2 * m.x + TH3 * ((s.x >= EPS) ? s.x : 0.0f);
        res.y = p.y + TH2 * m.y + TH3 * ((s.y >= EPS) ? s.y : 0.0f);
        res.z = p.z + TH2 * m.z + TH3 * ((s.z >= EPS) ? s.z : 0.0f);
        res.w = p.w + TH2 * m.w + TH3 * ((s.w >= EPS) ? s.w : 0.0f);
        o[fi] = res;
    }
}

extern "C" void kernel_launch(void* const* d_in, const int* in_sizes, int n_in,
                              void* d_out, int out_size, void* d_ws, size_t ws_size,
                              hipStream_t stream) {
    const int* idx = (const int*)d_in[1];     // [2,E] flat: src then dst
    const float* attr = (const float*)d_in[2];
    int E = in_sizes[1] / 2;

    char* ws = (char*)d_ws;
    int*   counts  = (int*)(ws);
    int*   row_ptr = (int*)(ws + (16 << 10));
    int*   cursor  = (int*)(ws + (48 << 10));
    int*   col     = (int*)(ws + (64 << 10));
    float* val     = (float*)(ws + (64 << 10) + (size_t)E * sizeof(int));
    float* m2      = (float*)(ws + (2 << 20));
    float* out     = (float*)d_out;

    hipMemsetAsync(counts, 0, N_NODES * sizeof(int), stream);
    hist_kernel<<<(E + 255) / 256, 256, 0, stream>>>(idx, E, counts);
    scan_kernel<<<1, 1024, 0, stream>>>(counts, row_ptr, cursor);
    scatter_kernel<<<(E + 255) / 256, 256, 0, stream>>>(idx, attr, E, cursor, col, val);
    m2_kernel<<<N_NODES, 256, 0, stream>>>(row_ptr, col, val, m2);
    out_kernel<<<N_NODES, 256, 0, stream>>>(row_ptr, col, val, m2, out);
}

// Round 2
// 208.028 us; speedup vs baseline: 2.1097x; 2.1097x over previous
//
#include <hip/hip_runtime.h>

#define N_NODES 4096
#define EPS 0.005f
#define TH0 0.4f
#define TH1 0.24f
#define TH2 0.144f
#define TH3 0.0864f
#define JTILE 512
#define NTILES (N_NODES / JTILE)

// ws layout (byte offsets):
//   0        counts  int[4096]          (zeroed via hipMemsetAsync)
//   16K      row_ptr int[4097]
//   48K      cursor  int[4096]
//   64K      col     int[E]             (E = 131072 -> 512KB)
//   64K+4E   val     float[E]           (512KB)
//   2M       m2      bf16[N*N]          (32MB, dense thresholded A@A, bf16)

static __device__ __forceinline__ float bf2f(unsigned short u) {
    union { unsigned int i; float f; } x;
    x.i = ((unsigned int)u) << 16;
    return x.f;
}

static __device__ __forceinline__ unsigned short f2bf(float f) {
    union { float f; unsigned int i; } x;
    x.f = f;
    unsigned int r = x.i + 0x7fff + ((x.i >> 16) & 1u);  // RNE; inputs finite >=0
    return (unsigned short)(r >> 16);
}

__global__ void hist_kernel(const int* __restrict__ idx, int E,
                            int* __restrict__ counts) {
    int e = blockIdx.x * blockDim.x + threadIdx.x;
    if (e < E) atomicAdd(&counts[idx[e]], 1);
}

__global__ __launch_bounds__(1024)
void scan_kernel(const int* __restrict__ counts, int* __restrict__ row_ptr,
                 int* __restrict__ cursor) {
    __shared__ int lds[1024];
    int t = threadIdx.x;
    int c0 = counts[4 * t + 0];
    int c1 = counts[4 * t + 1];
    int c2 = counts[4 * t + 2];
    int c3 = counts[4 * t + 3];
    int s = c0 + c1 + c2 + c3;
    lds[t] = s;
    __syncthreads();
    for (int off = 1; off < 1024; off <<= 1) {
        int v = 0;
        if (t >= off) v = lds[t - off];
        __syncthreads();
        lds[t] += v;
        __syncthreads();
    }
    int incl = lds[t];
    int base = incl - s;
    int r0 = base;
    int r1 = base + c0;
    int r2 = r1 + c1;
    int r3 = r2 + c2;
    row_ptr[4 * t + 0] = r0;  cursor[4 * t + 0] = r0;
    row_ptr[4 * t + 1] = r1;  cursor[4 * t + 1] = r1;
    row_ptr[4 * t + 2] = r2;  cursor[4 * t + 2] = r2;
    row_ptr[4 * t + 3] = r3;  cursor[4 * t + 3] = r3;
    if (t == 1023) row_ptr[N_NODES] = incl;
}

__global__ void scatter_kernel(const int* __restrict__ idx,
                               const float* __restrict__ attr, int E,
                               int* __restrict__ cursor, int* __restrict__ col,
                               float* __restrict__ val) {
    int e = blockIdx.x * blockDim.x + threadIdx.x;
    if (e < E) {
        int s = idx[e];
        int d = idx[e + E];
        int pos = atomicAdd(&cursor[s], 1);
        col[pos] = d;
        val[pos] = attr[e];
    }
}

// M2 = threshold(A @ A) in bf16. One block per row; 4 waves process 4
// neighbor rows concurrently, lane-parallel over each neighbor's edges.
__global__ __launch_bounds__(256)
void m2_kernel(const int* __restrict__ row_ptr, const int* __restrict__ col,
               const float* __restrict__ val, unsigned short* __restrict__ m2) {
    __shared__ float acc[N_NODES];
    __shared__ int   kcol[64];
    __shared__ float kval[64];
    __shared__ int   kf0[64];
    __shared__ int   kf1[64];
    int i = blockIdx.x;
    int t = threadIdx.x;
    for (int j = t; j < N_NODES; j += 256) acc[j] = 0.0f;
    __syncthreads();
    int e0 = row_ptr[i], e1 = row_ptr[i + 1];
    int wave = t >> 6, lane = t & 63;
    for (int base = e0; base < e1; base += 64) {
        int n = min(64, e1 - base);
        if (t < n) {
            int k = col[base + t];
            kcol[t] = k;
            kval[t] = val[base + t];
            kf0[t] = row_ptr[k];
            kf1[t] = row_ptr[k + 1];
        }
        __syncthreads();
        for (int q = wave; q < n; q += 4) {
            float a = kval[q];
            int f1 = kf1[q];
            for (int f = kf0[q] + lane; f < f1; f += 64) {
                atomicAdd(&acc[col[f]], a * val[f]);
            }
        }
        __syncthreads();
    }
    size_t rb = (size_t)i * N_NODES;
    for (int j = t; j < N_NODES; j += 256) {
        float v = acc[j];
        m2[rb + j] = (v >= EPS) ? f2bf(v) : (unsigned short)0;
    }
}

// out[i, jb:jb+512] = TH0*P0 + TH1*A + TH2*M2 + TH3*thr(A @ M2)
// One block per (row, column-tile). Tile-major dispatch (blockIdx.x = row
// fastest) keeps the 4 MB bf16 tile slice resident in each XCD's L2.
__global__ __launch_bounds__(128)
void out_kernel(const int* __restrict__ row_ptr, const int* __restrict__ col,
                const float* __restrict__ val,
                const unsigned short* __restrict__ m2,
                float* __restrict__ out) {
    __shared__ float ap[JTILE];
    __shared__ int   kcol[128];
    __shared__ float kval[128];
    int i = blockIdx.x;
    int jb = blockIdx.y * JTILE;
    int t = threadIdx.x;
    for (int j = t; j < JTILE; j += 128) ap[j] = 0.0f;
    __syncthreads();
    int e0 = row_ptr[i], e1 = row_ptr[i + 1];
    float4 acc = make_float4(0.f, 0.f, 0.f, 0.f);
    for (int base = e0; base < e1; base += 128) {
        int n = min(128, e1 - base);
        if (t < n) {
            int c = col[base + t];
            float v = val[base + t];
            kcol[t] = c;
            kval[t] = v;
            int cl = c - jb;
            if ((unsigned)cl < (unsigned)JTILE)
                atomicAdd(&ap[cl], TH0 + TH1 * v);   // P0 + A (dups accumulate)
        }
        __syncthreads();
        for (int q = 0; q < n; q++) {
            int k = kcol[q];
            float a = kval[q];
            const ushort4* r = (const ushort4*)(m2 + (size_t)k * N_NODES + jb);
            ushort4 u = r[t];
            acc.x = fmaf(a, bf2f(u.x), acc.x);
            acc.y = fmaf(a, bf2f(u.y), acc.y);
            acc.z = fmaf(a, bf2f(u.z), acc.z);
            acc.w = fmaf(a, bf2f(u.w), acc.w);
        }
        __syncthreads();
    }
    const ushort4* mi = (const ushort4*)(m2 + (size_t)i * N_NODES + jb);
    ushort4 um = mi[t];
    const float4* apv = (const float4*)ap;
    float4 p = apv[t];
    float4 res;
    res.x = p.x + TH2 * bf2f(um.x) + TH3 * ((acc.x >= EPS) ? acc.x : 0.0f);
    res.y = p.y + TH2 * bf2f(um.y) + TH3 * ((acc.y >= EPS) ? acc.y : 0.0f);
    res.z = p.z + TH2 * bf2f(um.z) + TH3 * ((acc.z >= EPS) ? acc.z : 0.0f);
    res.w = p.w + TH2 * bf2f(um.w) + TH3 * ((acc.w >= EPS) ? acc.w : 0.0f);
    ((float4*)(out + (size_t)i * N_NODES + jb))[t] = res;
}

extern "C" void kernel_launch(void* const* d_in, const int* in_sizes, int n_in,
                              void* d_out, int out_size, void* d_ws, size_t ws_size,
                              hipStream_t stream) {
    const int* idx = (const int*)d_in[1];     // [2,E] flat: src then dst
    const float* attr = (const float*)d_in[2];
    int E = in_sizes[1] / 2;

    char* ws = (char*)d_ws;
    int*   counts  = (int*)(ws);
    int*   row_ptr = (int*)(ws + (16 << 10));
    int*   cursor  = (int*)(ws + (48 << 10));
    int*   col     = (int*)(ws + (64 << 10));
    float* val     = (float*)(ws + (64 << 10) + (size_t)E * sizeof(int));
    unsigned short* m2 = (unsigned short*)(ws + (2 << 20));
    float* out     = (float*)d_out;

    hipMemsetAsync(counts, 0, N_NODES * sizeof(int), stream);
    hist_kernel<<<(E + 255) / 256, 256, 0, stream>>>(idx, E, counts);
    scan_kernel<<<1, 1024, 0, stream>>>(counts, row_ptr, cursor);
    scatter_kernel<<<(E + 255) / 256, 256, 0, stream>>>(idx, attr, E, cursor, col, val);
    m2_kernel<<<N_NODES, 256, 0, stream>>>(row_ptr, col, val, m2);
    out_kernel<<<dim3(N_NODES, NTILES), 128, 0, stream>>>(row_ptr, col, val, m2, out);
}

// Round 3
// 203.425 us; speedup vs baseline: 2.1574x; 1.0226x over previous
//
#include <hip/hip_runtime.h>

#define N_NODES 4096
#define EPS 0.005f
#define TH0 0.4f
#define TH1 0.24f
#define TH2 0.144f
#define TH3 0.0864f
#define JTILE 512
#define NTILES (N_NODES / JTILE)
#define CPAD 16   // counters padded to one per 64B line (kills atomic line contention)

// ws layout (byte offsets):
//   0      counts  int[4096*16] padded  (256KB, zeroed via hipMemsetAsync)
//   256K   cursor  int[4096*16] padded  (256KB)
//   512K   row_ptr int[4097]
//   576K   col     int[E]               (512KB)
//   1088K  val     float[E]             (512KB)
//   2M     m2      bf16[N*N]            (32MB, dense thresholded A@A)

static __device__ __forceinline__ float bf2f(unsigned short u) {
    union { unsigned int i; float f; } x;
    x.i = ((unsigned int)u) << 16;
    return x.f;
}

static __device__ __forceinline__ unsigned short f2bf(float f) {
    union { float f; unsigned int i; } x;
    x.f = f;
    unsigned int r = x.i + 0x7fff + ((x.i >> 16) & 1u);  // RNE; inputs finite >=0
    return (unsigned short)(r >> 16);
}

__global__ void hist_kernel(const int* __restrict__ idx, int E,
                            int* __restrict__ counts) {
    int e = blockIdx.x * blockDim.x + threadIdx.x;
    if (e < E) atomicAdd(&counts[idx[e] * CPAD], 1);
}

__global__ __launch_bounds__(1024)
void scan_kernel(const int* __restrict__ counts, int* __restrict__ row_ptr,
                 int* __restrict__ cursor) {
    __shared__ int lds[1024];
    int t = threadIdx.x;
    int c0 = counts[(4 * t + 0) * CPAD];
    int c1 = counts[(4 * t + 1) * CPAD];
    int c2 = counts[(4 * t + 2) * CPAD];
    int c3 = counts[(4 * t + 3) * CPAD];
    int s = c0 + c1 + c2 + c3;
    lds[t] = s;
    __syncthreads();
    for (int off = 1; off < 1024; off <<= 1) {
        int v = 0;
        if (t >= off) v = lds[t - off];
        __syncthreads();
        lds[t] += v;
        __syncthreads();
    }
    int incl = lds[t];
    int base = incl - s;
    int r0 = base;
    int r1 = base + c0;
    int r2 = r1 + c1;
    int r3 = r2 + c2;
    row_ptr[4 * t + 0] = r0;  cursor[(4 * t + 0) * CPAD] = r0;
    row_ptr[4 * t + 1] = r1;  cursor[(4 * t + 1) * CPAD] = r1;
    row_ptr[4 * t + 2] = r2;  cursor[(4 * t + 2) * CPAD] = r2;
    row_ptr[4 * t + 3] = r3;  cursor[(4 * t + 3) * CPAD] = r3;
    if (t == 1023) row_ptr[N_NODES] = incl;
}

__global__ void scatter_kernel(const int* __restrict__ idx,
                               const float* __restrict__ attr, int E,
                               int* __restrict__ cursor, int* __restrict__ col,
                               float* __restrict__ val) {
    int e = blockIdx.x * blockDim.x + threadIdx.x;
    if (e < E) {
        int s = idx[e];
        int d = idx[e + E];
        int pos = atomicAdd(&cursor[s * CPAD], 1);
        col[pos] = d;
        val[pos] = attr[e];
    }
}

// M2 = threshold(A @ A) in bf16. One block per row. 8-lane groups each own
// one neighbor -> 32 neighbors in flight concurrently (short latency chains).
__global__ __launch_bounds__(256)
void m2_kernel(const int* __restrict__ row_ptr, const int* __restrict__ col,
               const float* __restrict__ val, unsigned short* __restrict__ m2) {
    __shared__ float acc[N_NODES];
    __shared__ int   kcol[64];
    __shared__ float kval[64];
    __shared__ int   kf0[64];
    __shared__ int   kf1[64];
    int i = blockIdx.x;
    int t = threadIdx.x;
    for (int j = t; j < N_NODES; j += 256) acc[j] = 0.0f;
    __syncthreads();
    int e0 = row_ptr[i], e1 = row_ptr[i + 1];
    int gid = t >> 3, gl = t & 7;            // 32 groups of 8 lanes
    for (int base = e0; base < e1; base += 64) {
        int n = min(64, e1 - base);
        if (t < n) {
            int k = col[base + t];
            kcol[t] = k;
            kval[t] = val[base + t];
            kf0[t] = row_ptr[k];
            kf1[t] = row_ptr[k + 1];
        }
        __syncthreads();
        for (int q = gid; q < n; q += 32) {
            float a = kval[q];
            int f1 = kf1[q];
            for (int f = kf0[q] + gl; f < f1; f += 8) {
                atomicAdd(&acc[col[f]], a * val[f]);
            }
        }
        __syncthreads();
    }
    size_t rb = (size_t)i * N_NODES;
    for (int j = t; j < N_NODES; j += 256) {
        float v = acc[j];
        m2[rb + j] = (v >= EPS) ? f2bf(v) : (unsigned short)0;
    }
}

// out[i, jb:jb+512] = TH0*P0 + TH1*A + TH2*M2 + TH3*thr(A @ M2)
// One block per (row, column-tile); tile-major dispatch keeps the 4MB bf16
// tile slice resident per-XCD L2. Neighbor batch padded to x4 + manual
// unroll-4 -> 4 independent gather loads in flight per thread.
__global__ __launch_bounds__(128)
void out_kernel(const int* __restrict__ row_ptr, const int* __restrict__ col,
                const float* __restrict__ val,
                const unsigned short* __restrict__ m2,
                float* __restrict__ out) {
    __shared__ float ap[JTILE];
    __shared__ int   kcol[128];
    __shared__ float kval[128];
    int i = blockIdx.x;
    int jb = blockIdx.y * JTILE;
    int t = threadIdx.x;
    for (int j = t; j < JTILE; j += 128) ap[j] = 0.0f;
    __syncthreads();
    int e0 = row_ptr[i], e1 = row_ptr[i + 1];
    float4 acc = make_float4(0.f, 0.f, 0.f, 0.f);
    for (int base = e0; base < e1; base += 128) {
        int n = min(128, e1 - base);
        int n4 = (n + 3) & ~3;
        if (t < n) {
            int c = col[base + t];
            float v = val[base + t];
            kcol[t] = c;
            kval[t] = v;
            int cl = c - jb;
            if ((unsigned)cl < (unsigned)JTILE)
                atomicAdd(&ap[cl], TH0 + TH1 * v);   // P0 + A (dups accumulate)
        } else if (t < n4) {
            kcol[t] = 0;
            kval[t] = 0.0f;     // zero-weight pad: exact no-op in fma
        }
        __syncthreads();
        for (int q = 0; q < n4; q += 4) {
            int   k0 = kcol[q + 0]; float a0 = kval[q + 0];
            int   k1 = kcol[q + 1]; float a1 = kval[q + 1];
            int   k2 = kcol[q + 2]; float a2 = kval[q + 2];
            int   k3 = kcol[q + 3]; float a3 = kval[q + 3];
            ushort4 u0 = ((const ushort4*)(m2 + (size_t)k0 * N_NODES + jb))[t];
            ushort4 u1 = ((const ushort4*)(m2 + (size_t)k1 * N_NODES + jb))[t];
            ushort4 u2 = ((const ushort4*)(m2 + (size_t)k2 * N_NODES + jb))[t];
            ushort4 u3 = ((const ushort4*)(m2 + (size_t)k3 * N_NODES + jb))[t];
            acc.x = fmaf(a0, bf2f(u0.x), acc.x);
            acc.y = fmaf(a0, bf2f(u0.y), acc.y);
            acc.z = fmaf(a0, bf2f(u0.z), acc.z);
            acc.w = fmaf(a0, bf2f(u0.w), acc.w);
            acc.x = fmaf(a1, bf2f(u1.x), acc.x);
            acc.y = fmaf(a1, bf2f(u1.y), acc.y);
            acc.z = fmaf(a1, bf2f(u1.z), acc.z);
            acc.w = fmaf(a1, bf2f(u1.w), acc.w);
            acc.x = fmaf(a2, bf2f(u2.x), acc.x);
            acc.y = fmaf(a2, bf2f(u2.y), acc.y);
            acc.z = fmaf(a2, bf2f(u2.z), acc.z);
            acc.w = fmaf(a2, bf2f(u2.w), acc.w);
            acc.x = fmaf(a3, bf2f(u3.x), acc.x);
            acc.y = fmaf(a3, bf2f(u3.y), acc.y);
            acc.z = fmaf(a3, bf2f(u3.z), acc.z);
            acc.w = fmaf(a3, bf2f(u3.w), acc.w);
        }
        __syncthreads();
    }
    const ushort4* mi = (const ushort4*)(m2 + (size_t)i * N_NODES + jb);
    ushort4 um = mi[t];
    const float4* apv = (const float4*)ap;
    float4 p = apv[t];
    float4 res;
    res.x = p.x + TH2 * bf2f(um.x) + TH3 * ((acc.x >= EPS) ? acc.x : 0.0f);
    res.y = p.y + TH2 * bf2f(um.y) + TH3 * ((acc.y >= EPS) ? acc.y : 0.0f);
    res.z = p.z + TH2 * bf2f(um.z) + TH3 * ((acc.z >= EPS) ? acc.z : 0.0f);
    res.w = p.w + TH2 * bf2f(um.w) + TH3 * ((acc.w >= EPS) ? acc.w : 0.0f);
    ((float4*)(out + (size_t)i * N_NODES + jb))[t] = res;
}

extern "C" void kernel_launch(void* const* d_in, const int* in_sizes, int n_in,
                              void* d_out, int out_size, void* d_ws, size_t ws_size,
                              hipStream_t stream) {
    const int* idx = (const int*)d_in[1];     // [2,E] flat: src then dst
    const float* attr = (const float*)d_in[2];
    int E = in_sizes[1] / 2;

    char* ws = (char*)d_ws;
    int*   counts  = (int*)(ws);
    int*   cursor  = (int*)(ws + (256 << 10));
    int*   row_ptr = (int*)(ws + (512 << 10));
    int*   col     = (int*)(ws + (576 << 10));
    float* val     = (float*)(ws + (1088 << 10));
    unsigned short* m2 = (unsigned short*)(ws + (2 << 20));
    float* out     = (float*)d_out;

    hipMemsetAsync(counts, 0, N_NODES * CPAD * sizeof(int), stream);
    hist_kernel<<<(E + 255) / 256, 256, 0, stream>>>(idx, E, counts);
    scan_kernel<<<1, 1024, 0, stream>>>(counts, row_ptr, cursor);
    scatter_kernel<<<(E + 255) / 256, 256, 0, stream>>>(idx, attr, E, cursor, col, val);
    m2_kernel<<<N_NODES, 256, 0, stream>>>(row_ptr, col, val, m2);
    out_kernel<<<dim3(N_NODES, NTILES), 128, 0, stream>>>(row_ptr, col, val, m2, out);
}

// Round 4
// 202.617 us; speedup vs baseline: 2.1660x; 1.0040x over previous
//
#include <hip/hip_runtime.h>

#define N_NODES 4096
#define EPS 0.005f
#define TH0 0.4f
#define TH1 0.24f
#define TH2 0.144f
#define TH3 0.0864f
#define JTILE 512
#define NTILES (N_NODES / JTILE)
#define CPAD 16      // one counter per 64B line
#define EPADMAX (131072 + 4 * N_NODES)   // padded CSR capacity

// ws layout (byte offsets):
//   0      counts  int[4096*16]   256KB (memset 0)
//   256K   cursor  int[4096*16]   256KB
//   512K   row4    int[4097]      (4-aligned padded CSR row starts)
//   576K   col2    int[EPADMAX]   576KB (memset 0; pads stay col=0)
//   1152K  val2    float[EPADMAX] 576KB (memset 0; pads stay val=0 -> fma no-op)
//   2M     m2      bf16[N*N]      32MB dense thresholded A@A

static __device__ __forceinline__ float bf2f(unsigned short u) {
    union { unsigned int i; float f; } x;
    x.i = ((unsigned int)u) << 16;
    return x.f;
}

static __device__ __forceinline__ unsigned short f2bf(float f) {
    union { float f; unsigned int i; } x;
    x.f = f;
    unsigned int r = x.i + 0x7fff + ((x.i >> 16) & 1u);  // RNE; finite >=0
    return (unsigned short)(r >> 16);
}

__global__ void hist_kernel(const int* __restrict__ idx, int E,
                            int* __restrict__ counts) {
    int e = blockIdx.x * blockDim.x + threadIdx.x;
    if (e < E) atomicAdd(&counts[idx[e] * CPAD], 1);
}

__global__ __launch_bounds__(1024)
void scan_kernel(const int* __restrict__ counts, int* __restrict__ row4,
                 int* __restrict__ cursor) {
    __shared__ int lds[1024];
    int t = threadIdx.x;
    // padded lengths: round each row's count up to x4
    int p0 = (counts[(4 * t + 0) * CPAD] + 3) & ~3;
    int p1 = (counts[(4 * t + 1) * CPAD] + 3) & ~3;
    int p2 = (counts[(4 * t + 2) * CPAD] + 3) & ~3;
    int p3 = (counts[(4 * t + 3) * CPAD] + 3) & ~3;
    int s = p0 + p1 + p2 + p3;
    lds[t] = s;
    __syncthreads();
    for (int off = 1; off < 1024; off <<= 1) {
        int v = 0;
        if (t >= off) v = lds[t - off];
        __syncthreads();
        lds[t] += v;
        __syncthreads();
    }
    int incl = lds[t];
    int base = incl - s;
    int r0 = base;
    int r1 = base + p0;
    int r2 = r1 + p1;
    int r3 = r2 + p2;
    row4[4 * t + 0] = r0;  cursor[(4 * t + 0) * CPAD] = r0;
    row4[4 * t + 1] = r1;  cursor[(4 * t + 1) * CPAD] = r1;
    row4[4 * t + 2] = r2;  cursor[(4 * t + 2) * CPAD] = r2;
    row4[4 * t + 3] = r3;  cursor[(4 * t + 3) * CPAD] = r3;
    if (t == 1023) row4[N_NODES] = incl;
}

__global__ void scatter_kernel(const int* __restrict__ idx,
                               const float* __restrict__ attr, int E,
                               int* __restrict__ cursor, int* __restrict__ col2,
                               float* __restrict__ val2) {
    int e = blockIdx.x * blockDim.x + threadIdx.x;
    if (e < E) {
        int s = idx[e];
        int d = idx[e + E];
        int pos = atomicAdd(&cursor[s * CPAD], 1);
        col2[pos] = d;
        val2[pos] = attr[e];
    }
}

// M2 = threshold(A @ A) in bf16. One block/row, dense LDS accumulator.
// unsafeAtomicAdd -> native ds_add_f32 (no IEEE CAS loop); b128 init/epilogue.
__global__ __launch_bounds__(256)
void m2_kernel(const int* __restrict__ row4, const int* __restrict__ col2,
               const float* __restrict__ val2, unsigned short* __restrict__ m2) {
    __shared__ float acc[N_NODES];
    __shared__ int   kcol[64];
    __shared__ float kval[64];
    __shared__ int   kf0[64];
    __shared__ int   kf1[64];
    int i = blockIdx.x;
    int t = threadIdx.x;
    float4 z = make_float4(0.f, 0.f, 0.f, 0.f);
    for (int j4 = t; j4 < N_NODES / 4; j4 += 256) ((float4*)acc)[j4] = z;
    __syncthreads();
    int e0 = row4[i], e1 = row4[i + 1];
    int gid = t >> 3, gl = t & 7;            // 32 groups x 8 lanes
    for (int base = e0; base < e1; base += 64) {
        int n = min(64, e1 - base);
        if (t < n) {
            int k = col2[base + t];
            kcol[t] = k;
            kval[t] = val2[base + t];
            kf0[t] = row4[k];
            kf1[t] = row4[k + 1];
        }
        __syncthreads();
        for (int q = gid; q < n; q += 32) {
            float a = kval[q];
            if (a > 0.0f) {                   // skip zero pads
                int f1 = kf1[q];
                for (int f = kf0[q] + gl; f < f1; f += 8) {
                    unsafeAtomicAdd(&acc[col2[f]], a * val2[f]);
                }
            }
        }
        __syncthreads();
    }
    size_t rb = (size_t)i * N_NODES;
    for (int j4 = t; j4 < N_NODES / 4; j4 += 256) {
        float4 v = ((const float4*)acc)[j4];
        ushort4 r;
        r.x = (v.x >= EPS) ? f2bf(v.x) : (unsigned short)0;
        r.y = (v.y >= EPS) ? f2bf(v.y) : (unsigned short)0;
        r.z = (v.z >= EPS) ? f2bf(v.z) : (unsigned short)0;
        r.w = (v.w >= EPS) ? f2bf(v.w) : (unsigned short)0;
        ((ushort4*)(m2 + rb))[j4] = r;
    }
}

// out[i, jb:jb+512] = TH0*P0 + TH1*A + TH2*M2 + TH3*thr(A @ M2)
// Flat grid, tile = blockIdx.x % 8: round-robin block->XCD mapping pins each
// column tile to one XCD -> each XCD L2-fills only its own 4MB m2 slice.
// Edge walk is wave-uniform (scalar addresses, padded x4, no LDS staging).
__global__ __launch_bounds__(128)
void out_kernel(const int* __restrict__ row4, const int* __restrict__ col2,
                const float* __restrict__ val2,
                const unsigned short* __restrict__ m2,
                float* __restrict__ out) {
    __shared__ float ap[JTILE];
    int lin = blockIdx.x;
    int tile = lin & 7;
    int i = lin >> 3;
    int jb = tile * JTILE;
    int t = threadIdx.x;
    for (int j = t; j < JTILE; j += 128) ap[j] = 0.0f;
    __syncthreads();
    int e0 = row4[i], e1 = row4[i + 1];
    // P0 + A scatter (guard val>0 excludes zero pads; dups accumulate)
    for (int e = e0 + t; e < e1; e += 128) {
        float v = val2[e];
        if (v > 0.0f) {
            int cl = col2[e] - jb;
            if ((unsigned)cl < (unsigned)JTILE)
                unsafeAtomicAdd(&ap[cl], TH0 + TH1 * v);
        }
    }
    // dense gather, 4 edges/iter, uniform scalar addressing
    float4 acc = make_float4(0.f, 0.f, 0.f, 0.f);
    const unsigned short* m2t = m2 + jb + 4 * t;
    for (int e = e0; e < e1; e += 4) {
        int4   kq = *(const int4*)(col2 + e);
        float4 aq = *(const float4*)(val2 + e);
        int k0 = __builtin_amdgcn_readfirstlane(kq.x);
        int k1 = __builtin_amdgcn_readfirstlane(kq.y);
        int k2 = __builtin_amdgcn_readfirstlane(kq.z);
        int k3 = __builtin_amdgcn_readfirstlane(kq.w);
        ushort4 u0 = *(const ushort4*)(m2t + (size_t)k0 * N_NODES);
        ushort4 u1 = *(const ushort4*)(m2t + (size_t)k1 * N_NODES);
        ushort4 u2 = *(const ushort4*)(m2t + (size_t)k2 * N_NODES);
        ushort4 u3 = *(const ushort4*)(m2t + (size_t)k3 * N_NODES);
        acc.x = fmaf(aq.x, bf2f(u0.x), acc.x);
        acc.y = fmaf(aq.x, bf2f(u0.y), acc.y);
        acc.z = fmaf(aq.x, bf2f(u0.z), acc.z);
        acc.w = fmaf(aq.x, bf2f(u0.w), acc.w);
        acc.x = fmaf(aq.y, bf2f(u1.x), acc.x);
        acc.y = fmaf(aq.y, bf2f(u1.y), acc.y);
        acc.z = fmaf(aq.y, bf2f(u1.z), acc.z);
        acc.w = fmaf(aq.y, bf2f(u1.w), acc.w);
        acc.x = fmaf(aq.z, bf2f(u2.x), acc.x);
        acc.y = fmaf(aq.z, bf2f(u2.y), acc.y);
        acc.z = fmaf(aq.z, bf2f(u2.z), acc.z);
        acc.w = fmaf(aq.z, bf2f(u2.w), acc.w);
        acc.x = fmaf(aq.w, bf2f(u3.x), acc.x);
        acc.y = fmaf(aq.w, bf2f(u3.y), acc.y);
        acc.z = fmaf(aq.w, bf2f(u3.z), acc.z);
        acc.w = fmaf(aq.w, bf2f(u3.w), acc.w);
    }
    __syncthreads();
    ushort4 um = ((const ushort4*)(m2 + (size_t)i * N_NODES + jb))[t];
    float4 p = ((const float4*)ap)[t];
    float4 res;
    res.x = p.x + TH2 * bf2f(um.x) + TH3 * ((acc.x >= EPS) ? acc.x : 0.0f);
    res.y = p.y + TH2 * bf2f(um.y) + TH3 * ((acc.y >= EPS) ? acc.y : 0.0f);
    res.z = p.z + TH2 * bf2f(um.z) + TH3 * ((acc.z >= EPS) ? acc.z : 0.0f);
    res.w = p.w + TH2 * bf2f(um.w) + TH3 * ((acc.w >= EPS) ? acc.w : 0.0f);
    ((float4*)(out + (size_t)i * N_NODES + jb))[t] = res;
}

extern "C" void kernel_launch(void* const* d_in, const int* in_sizes, int n_in,
                              void* d_out, int out_size, void* d_ws, size_t ws_size,
                              hipStream_t stream) {
    const int* idx = (const int*)d_in[1];     // [2,E] flat: src then dst
    const float* attr = (const float*)d_in[2];
    int E = in_sizes[1] / 2;

    char* ws = (char*)d_ws;
    int*   counts = (int*)(ws);
    int*   cursor = (int*)(ws + (256 << 10));
    int*   row4   = (int*)(ws + (512 << 10));
    int*   col2   = (int*)(ws + (576 << 10));
    float* val2   = (float*)(ws + (1152 << 10));
    unsigned short* m2 = (unsigned short*)(ws + (2 << 20));
    float* out    = (float*)d_out;

    hipMemsetAsync(counts, 0, N_NODES * CPAD * sizeof(int), stream);
    hipMemsetAsync(col2, 0, 2 * EPADMAX * sizeof(int), stream);  // col2+val2 contiguous
    hist_kernel<<<(E + 255) / 256, 256, 0, stream>>>(idx, E, counts);
    scan_kernel<<<1, 1024, 0, stream>>>(counts, row4, cursor);
    scatter_kernel<<<(E + 255) / 256, 256, 0, stream>>>(idx, attr, E, cursor, col2, val2);
    m2_kernel<<<N_NODES, 256, 0, stream>>>(row4, col2, val2, m2);
    out_kernel<<<N_NODES * NTILES, 128, 0, stream>>>(row4, col2, val2, m2, out);
}